// Round 5
// baseline (133491.772 us; speedup 1.0000x reference)
//
#include <hip/hip_runtime.h>

// MogLSTM T=1024, B=64, H=512, 2 layers, 5 mog steps.
// 4 batch row-groups x (2 layers x 32 col-slices) = 256 single-wave WGs.
// NO agent fences (they invalidate L2 on gfx95x). Activations cross XCDs
// via explicit sc0/sc1 (coherence-point) loads/stores + s_waitcnt; weights
// use cached loads and stay L2-resident. Barrier = slot store + 64-lane
// all-poll, spin-capped. hi/lo fp16 split (fp32-accurate), c/h in regs.

#define T_LEN 1024
#define BB 64
#define HH 512
#define NG 4
#define GWG 64
#define NWG (NG * GWG)
#define RPG 16
#define PAD 32
#define SPIN_CAP 500000

typedef __attribute__((ext_vector_type(8))) _Float16 f16x8;
typedef __attribute__((ext_vector_type(4))) float f32x4;

#define MW_N (2 * 5 * 512 * 512)
#define GW_N (2 * 2048 * 512)
#define ACT_N (2 * 64 * 512)

__device__ _Float16 g_mw_hi[MW_N];
__device__ _Float16 g_mw_lo[MW_N];
__device__ _Float16 g_wih_hi[GW_N];
__device__ _Float16 g_wih_lo[GW_N];
__device__ _Float16 g_whh_hi[GW_N];
__device__ _Float16 g_whh_lo[GW_N];
// activation planes: ONLY accessed via sc0/sc1 bypass ops inside main kernel
__device__ __align__(16) _Float16 g_xh[ACT_N], g_xl[ACT_N];   // x buf
__device__ __align__(16) _Float16 g_mh[ACT_N], g_ml[ACT_N];   // mogrified h
__device__ __align__(16) _Float16 g_hh[ACT_N], g_hl[ACT_N];   // lstm h state
__device__ int g_slots[NWG * PAD];

__device__ __forceinline__ float sigmoidf_(float z) {
    return 1.f / (1.f + expf(-z));
}
__device__ __forceinline__ float tanhf_(float z) {
    float a = fabsf(z);
    float e = expf(-2.f * a);
    float t = (1.f - e) / (1.f + e);
    return z >= 0.f ? t : -t;
}

// ---- cache-bypass (coherence point) access helpers ----
__device__ __forceinline__ f16x8 ld_cp(const _Float16* p) {
    f16x8 r;
    asm volatile("global_load_dwordx4 %0, %1, off sc0 sc1" : "=v"(r) : "v"(p));
    return r;
}
__device__ __forceinline__ unsigned ld_cp_u16(const _Float16* p) {
    unsigned r;
    asm volatile("global_load_ushort %0, %1, off sc0 sc1" : "=v"(r) : "v"(p));
    return r;
}
__device__ __forceinline__ void st_cp_u16(_Float16* p, _Float16 v) {
    asm volatile("global_store_short %0, %1, off sc0 sc1" :: "v"(p), "v"(v) : "memory");
}
__device__ __forceinline__ void wait_vm0() {
    asm volatile("s_waitcnt vmcnt(0)" ::: "memory");
    __builtin_amdgcn_sched_barrier(0);
}
__device__ __forceinline__ void st_hl(_Float16* ph, _Float16* pl, float v) {
    _Float16 h = (_Float16)v;
    _Float16 l2 = (_Float16)(v - (float)h);
    st_cp_u16(ph, h);
    st_cp_u16(pl, l2);
}

__global__ void prep_kernel(const float* __restrict__ mogW,
                            const float* __restrict__ Wih,
                            const float* __restrict__ Whh) {
    size_t tid = (size_t)blockIdx.x * blockDim.x + threadIdx.x;
    size_t gs = (size_t)gridDim.x * blockDim.x;
    for (size_t i = tid; i < MW_N; i += gs) {
        float w = mogW[i];
        _Float16 h = (_Float16)w;
        g_mw_hi[i] = h;
        g_mw_lo[i] = (_Float16)(w - (float)h);
    }
    for (size_t i = tid; i < GW_N; i += gs) {
        float w = Wih[i];
        _Float16 h = (_Float16)w;
        g_wih_hi[i] = h;
        g_wih_lo[i] = (_Float16)(w - (float)h);
        w = Whh[i];
        h = (_Float16)w;
        g_whh_hi[i] = h;
        g_whh_lo[i] = (_Float16)(w - (float)h);
    }
    for (size_t i = tid; i < ACT_N; i += gs) {
        g_xh[i] = (_Float16)0.f; g_xl[i] = (_Float16)0.f;
        g_mh[i] = (_Float16)0.f; g_ml[i] = (_Float16)0.f;
        g_hh[i] = (_Float16)0.f; g_hl[i] = (_Float16)0.f;
    }
    for (size_t i = tid; i < NWG * PAD; i += gs) g_slots[i] = 0;
}

// Single-hop group barrier: lane0 stores own slot, all 64 lanes poll the
// group's 64 slots 1:1. Relaxed atomics only (no cache-maintenance fences);
// data ordering is handled by wait_vm0() at call sites.
__device__ __forceinline__ void gbar(int slotbase, int myslot, int phase, bool* dead) {
    if (threadIdx.x == 0)
        __hip_atomic_store(&g_slots[(slotbase + myslot) * PAD], phase,
                           __ATOMIC_RELAXED, __HIP_MEMORY_SCOPE_AGENT);
    if (*dead) return;
    int* p = &g_slots[(slotbase + (int)threadIdx.x) * PAD];
    int guard = 0;
    while (!__all(__hip_atomic_load(p, __ATOMIC_RELAXED, __HIP_MEMORY_SCOPE_AGENT) >= phase)) {
        if (++guard > SPIN_CAP) { *dead = true; return; }
        __builtin_amdgcn_s_sleep(1);
    }
}

// [16 rows x 16 cols] over K=512, hi/lo 3-term. A from coherence point,
// B (weights) cached (L2-resident).
__device__ __forceinline__ f32x4 mogmm(const _Float16* sh, const _Float16* sl,
                                       const _Float16* bh_, const _Float16* bl_) {
    f16x8 Ah[16], Al[16];
#pragma unroll
    for (int kb = 0; kb < 16; ++kb) {
        Ah[kb] = ld_cp(sh + kb * 32);
        Al[kb] = ld_cp(sl + kb * 32);
    }
    wait_vm0();
    f32x4 acc = {0.f, 0.f, 0.f, 0.f};
#pragma unroll
    for (int kb = 0; kb < 16; ++kb) {
        f16x8 bh = *(const f16x8*)(bh_ + kb * 32);
        f16x8 bl = *(const f16x8*)(bl_ + kb * 32);
        acc = __builtin_amdgcn_mfma_f32_16x16x32_f16(Ah[kb], bh, acc, 0, 0, 0);
        acc = __builtin_amdgcn_mfma_f32_16x16x32_f16(Ah[kb], bl, acc, 0, 0, 0);
        acc = __builtin_amdgcn_mfma_f32_16x16x32_f16(Al[kb], bh, acc, 0, 0, 0);
    }
    return acc;
}

__global__ __launch_bounds__(64, 1) void moglstm_kernel(
    const float* __restrict__ input_seq,   // [T][B][H]
    const float* __restrict__ mogb,        // [2][5][H]
    const float* __restrict__ b_ih,        // [2][4H]
    const float* __restrict__ b_hh,        // [2][4H]
    float* __restrict__ out)               // outputs | last_h | last_c
{
    const int wg = blockIdx.x;
    const int g = wg >> 6;          // row-group 0..3 (rows g*16..g*16+15)
    const int u6 = wg & 63;
    const int l = u6 >> 5;          // layer 0/1 (pipelined, lag 1)
    const int c = u6 & 31;          // col-slice (16 cols); XCD = c%8
    const int lane = threadIdx.x;
    const int al = lane & 15;
    const int ah = lane >> 4;
    const int r0 = g * RPG;
    const int col = c * 16 + al;    // this lane's output column
    const int slotbase = g * GWG;

    const size_t aoff = (size_t)(r0 + al) * HH + ah * 8;   // A-frag offset
    const int lb = l * BB * HH;                            // layer act base

    _Float16* xh = g_xh + lb; _Float16* xl = g_xl + lb;
    _Float16* mh = g_mh + lb; _Float16* ml = g_ml + lb;
    _Float16* hh = g_hh + lb; _Float16* hl = g_hl + lb;

    int orow[4];
#pragma unroll
    for (int r = 0; r < 4; ++r) orow[r] = (r0 + ah * 4 + r) * HH + col;

    // per-lane constant biases
    float mbias[5];
#pragma unroll
    for (int m = 0; m < 5; ++m) mbias[m] = mogb[(l * 5 + m) * HH + col];
    const float bgi = b_ih[l*4*HH + 0*HH + col] + b_hh[l*4*HH + 0*HH + col];
    const float bgf = b_ih[l*4*HH + 1*HH + col] + b_hh[l*4*HH + 1*HH + col];
    const float bgg = b_ih[l*4*HH + 2*HH + col] + b_hh[l*4*HH + 2*HH + col];
    const float bgo = b_ih[l*4*HH + 3*HH + col] + b_hh[l*4*HH + 3*HH + col];

    // weight bases (pre-offset per lane); cached loads, L2-resident
    const size_t wrow = (size_t)col * HH + ah * 8;
    const _Float16* mwhB = g_mw_hi + (size_t)l * 5 * HH * HH + wrow;
    const _Float16* mwlB = g_mw_lo + (size_t)l * 5 * HH * HH + wrow;
    const _Float16* wihH = g_wih_hi + (size_t)l * 4 * HH * HH + wrow;
    const _Float16* wihL = g_wih_lo + (size_t)l * 4 * HH * HH + wrow;
    const _Float16* whhH = g_whh_hi + (size_t)l * 4 * HH * HH + wrow;
    const _Float16* whhL = g_whh_lo + (size_t)l * 4 * HH * HH + wrow;

    float c_reg[4] = {0.f, 0.f, 0.f, 0.f};
    float hreg[4] = {0.f, 0.f, 0.f, 0.f};   // own-col h state
    float xreg[4], mreg[4];                 // own-col x / mogrified-h
    bool dead = false;
    int phase = 0;

#define MOG_STAGE(mI, SH, SL, DH, DL, UE_EXPR)                                \
    {                                                                         \
        f32x4 acc = mogmm(SH + aoff, SL + aoff,                               \
                          mwhB + (size_t)(mI) * HH * HH,                      \
                          mwlB + (size_t)(mI) * HH * HH);                     \
        _Pragma("unroll")                                                     \
        for (int r = 0; r < 4; ++r) {                                         \
            float z = acc[r] + mbias[mI];                                     \
            float nv = 2.f * sigmoidf_(z) * (UE_EXPR);                        \
            if ((mI) & 1) mreg[r] = nv; else xreg[r] = nv;                    \
            st_hl(DH + orow[r], DL + orow[r], nv);                            \
        }                                                                     \
        wait_vm0();                                                           \
    }

    for (int s = 0; s <= T_LEN; ++s) {
        const int t = (l == 0) ? s : s - 1;
        const bool active = (t >= 0) && (t < T_LEN);

        // ---- stage 0: x = 2*sig(h @ W0^T + b0) * x_in ----
        if (active) {
            float u_in[4];
            if (l == 0) {
#pragma unroll
                for (int r = 0; r < 4; ++r)
                    u_in[r] = input_seq[(size_t)t * BB * HH + orow[r]];
                MOG_STAGE(0, hh, hl, xh, xl, u_in[r]);
            } else {
                unsigned uhb[4], ulb[4];
#pragma unroll
                for (int r = 0; r < 4; ++r) {      // h1(t) from layer-0 planes
                    uhb[r] = ld_cp_u16(g_hh + orow[r]);
                    ulb[r] = ld_cp_u16(g_hl + orow[r]);
                }
                // mogmm's wait_vm0 drains these before use below
                f32x4 acc = mogmm(hh + aoff, hl + aoff, mwhB, mwlB);
#pragma unroll
                for (int r = 0; r < 4; ++r) {
                    float uv = (float)__builtin_bit_cast(_Float16, (unsigned short)uhb[r])
                             + (float)__builtin_bit_cast(_Float16, (unsigned short)ulb[r]);
                    u_in[r] = uv;
                    float z = acc[r] + mbias[0];
                    float nv = 2.f * sigmoidf_(z) * uv;
                    xreg[r] = nv;
                    st_hl(xh + orow[r], xl + orow[r], nv);
                }
                wait_vm0();
            }
        }
        gbar(slotbase, u6, ++phase, &dead);

        // ---- stage 1: hm = 2*sig(x @ W1^T + b1) * h ----
        if (active) MOG_STAGE(1, xh, xl, mh, ml, hreg[r]);
        gbar(slotbase, u6, ++phase, &dead);

        // ---- stage 2: x = 2*sig(hm @ W2^T + b2) * x ----
        if (active) MOG_STAGE(2, mh, ml, xh, xl, xreg[r]);
        gbar(slotbase, u6, ++phase, &dead);

        // ---- stage 3: hm = 2*sig(x @ W3^T + b3) * hm ----
        if (active) MOG_STAGE(3, xh, xl, mh, ml, mreg[r]);
        gbar(slotbase, u6, ++phase, &dead);

        // ---- stage 4: x = 2*sig(hm @ W4^T + b4) * x ----
        if (active) MOG_STAGE(4, mh, ml, xh, xl, xreg[r]);
        gbar(slotbase, u6, ++phase, &dead);

        // ---- gates + LSTM update ----
        if (active) {
            f32x4 a0 = {0.f,0.f,0.f,0.f}, a1 = {0.f,0.f,0.f,0.f};
            f32x4 a2 = {0.f,0.f,0.f,0.f}, a3 = {0.f,0.f,0.f,0.f};
            {   // x_final @ Wih^T
                f16x8 Ah[16], Al[16];
#pragma unroll
                for (int kb = 0; kb < 16; ++kb) {
                    Ah[kb] = ld_cp(xh + aoff + kb * 32);
                    Al[kb] = ld_cp(xl + aoff + kb * 32);
                }
                wait_vm0();
#pragma unroll
                for (int kb = 0; kb < 16; ++kb) {
#pragma unroll
                    for (int gi = 0; gi < 4; ++gi) {
                        f16x8 bh = *(const f16x8*)(wihH + (size_t)gi * HH * HH + kb * 32);
                        f16x8 bl = *(const f16x8*)(wihL + (size_t)gi * HH * HH + kb * 32);
                        f32x4* A = gi == 0 ? &a0 : gi == 1 ? &a1 : gi == 2 ? &a2 : &a3;
                        *A = __builtin_amdgcn_mfma_f32_16x16x32_f16(Ah[kb], bh, *A, 0, 0, 0);
                        *A = __builtin_amdgcn_mfma_f32_16x16x32_f16(Ah[kb], bl, *A, 0, 0, 0);
                        *A = __builtin_amdgcn_mfma_f32_16x16x32_f16(Al[kb], bh, *A, 0, 0, 0);
                    }
                }
            }
            {   // + hm_final @ Whh^T
                f16x8 Ah[16], Al[16];
#pragma unroll
                for (int kb = 0; kb < 16; ++kb) {
                    Ah[kb] = ld_cp(mh + aoff + kb * 32);
                    Al[kb] = ld_cp(ml + aoff + kb * 32);
                }
                wait_vm0();
#pragma unroll
                for (int kb = 0; kb < 16; ++kb) {
#pragma unroll
                    for (int gi = 0; gi < 4; ++gi) {
                        f16x8 bh = *(const f16x8*)(whhH + (size_t)gi * HH * HH + kb * 32);
                        f16x8 bl = *(const f16x8*)(whhL + (size_t)gi * HH * HH + kb * 32);
                        f32x4* A = gi == 0 ? &a0 : gi == 1 ? &a1 : gi == 2 ? &a2 : &a3;
                        *A = __builtin_amdgcn_mfma_f32_16x16x32_f16(Ah[kb], bh, *A, 0, 0, 0);
                        *A = __builtin_amdgcn_mfma_f32_16x16x32_f16(Ah[kb], bl, *A, 0, 0, 0);
                        *A = __builtin_amdgcn_mfma_f32_16x16x32_f16(Al[kb], bh, *A, 0, 0, 0);
                    }
                }
            }
#pragma unroll
            for (int r = 0; r < 4; ++r) {
                float ig = sigmoidf_(a0[r] + bgi);
                float fg = sigmoidf_(a1[r] + bgf);
                float gg = tanhf_(a2[r] + bgg);
                float og = sigmoidf_(a3[r] + bgo);
                float cc = fg * c_reg[r] + ig * gg;
                c_reg[r] = cc;
                float h = og * tanhf_(cc);
                hreg[r] = h;
                st_hl(hh + orow[r], hl + orow[r], h);
                if (l == 1)
                    out[(size_t)t * BB * HH + orow[r]] = h;       // plain store
                if (t == T_LEN - 1) {
                    out[(size_t)T_LEN * BB * HH + (size_t)l * BB * HH + orow[r]] = h;
                    out[(size_t)T_LEN * BB * HH + 2u * BB * HH + (size_t)l * BB * HH + orow[r]] = cc;
                }
            }
            wait_vm0();
        }
        gbar(slotbase, u6, ++phase, &dead);
    }
#undef MOG_STAGE
}

extern "C" void kernel_launch(void* const* d_in, const int* in_sizes, int n_in,
                              void* d_out, int out_size, void* d_ws, size_t ws_size,
                              hipStream_t stream) {
    const float* input_seq = (const float*)d_in[0];
    const float* mogW = (const float*)d_in[1];
    const float* mogb = (const float*)d_in[2];
    const float* W_ih = (const float*)d_in[3];
    const float* W_hh = (const float*)d_in[4];
    const float* b_ih = (const float*)d_in[5];
    const float* b_hh = (const float*)d_in[6];
    float* out = (float*)d_out;
    (void)d_ws; (void)ws_size;

    hipLaunchKernelGGL(prep_kernel, dim3(1024), dim3(256), 0, stream,
                       mogW, W_ih, W_hh);
    hipLaunchKernelGGL(moglstm_kernel, dim3(NWG), dim3(64), 0, stream,
                       input_seq, mogb, b_ih, b_hh, out);
}